// Round 1
// 731.322 us; speedup vs baseline: 1.0878x; 1.0878x over previous
//
#include <hip/hip_runtime.h>
#include <math.h>

#define NN  100000
#define NE  3200000
#define FIN 512
#define HID 256
#define NC  40

#define NBUK 391                      // ceil(NN/256), bucket = row>>8
#define SPB  9472                     // fixed slots per bucket (mean 8184 + 14 sigma)
#define BIN_BLOCKS 512
#define CHUNK ((NE + BIN_BLOCKS - 1) / BIN_BLOCKS)   // 6250
#define COLMASK 0x1FFFF

typedef __attribute__((ext_vector_type(8))) short short8;
typedef __attribute__((ext_vector_type(4))) float f32x4;

__device__ inline float bf2f(unsigned short u) {
    unsigned int x = ((unsigned int)u) << 16;
    return __builtin_bit_cast(float, x);
}
__device__ inline unsigned short f2bfu(float f) {
    unsigned int x = __builtin_bit_cast(unsigned int, f);
    unsigned int r = (x + 0x7fffu + ((x >> 16) & 1u)) >> 16;
    return (unsigned short)r;
}
__device__ inline signed char q8(float v, float s) {
    int q = (int)rintf(v * s);
    q = max(-127, min(127, q));
    return (signed char)q;
}

// ---------------- bin edges into fixed-stride bucket staging (no pre-scan) ----------------
__global__ __launch_bounds__(256) void k_bin(const int* __restrict__ er, const int* __restrict__ ec,
                                             const float* __restrict__ ev, int* __restrict__ bcnt,
                                             int2* __restrict__ spack) {
    __shared__ int hist[NBUK];
    __shared__ int base[NBUK];
    __shared__ int lcur[NBUK];
    for (int i = threadIdx.x; i < NBUK; i += 256) { hist[i] = 0; lcur[i] = 0; }
    __syncthreads();
    int start = blockIdx.x * CHUNK;
    int end = min(start + CHUNK, NE);
    for (int e = start + threadIdx.x; e < end; e += 256)
        atomicAdd(&hist[er[e] >> 8], 1);
    __syncthreads();
    for (int i = threadIdx.x; i < NBUK; i += 256) {
        int h = hist[i];
        base[i] = h ? atomicAdd(&bcnt[i], h) : 0;
    }
    __syncthreads();
    for (int e = start + threadIdx.x; e < end; e += 256) {
        int r = er[e];
        int b = r >> 8;
        int ofs = atomicAdd(&lcur[b], 1);
        int2 p;
        p.x = ((r & 255) << 17) | ec[e];
        p.y = __builtin_bit_cast(int, ev[e]);
        spack[(size_t)b * SPB + base[b] + ofs] = p;
    }
}

// ---------------- fine CSR within each bucket ----------------
__global__ __launch_bounds__(256) void k_finecsr(const int2* __restrict__ spack, const int* __restrict__ bcnt,
                                                 int2* __restrict__ cpack,
                                                 int* __restrict__ row_beg, int* __restrict__ row_cnt) {
    __shared__ int cnt[256];
    __shared__ int sm[256];
    __shared__ int cur[256];
    int tid = threadIdx.x;
    int buk = blockIdx.x;
    size_t bb = (size_t)buk * SPB;
    int n = min(bcnt[buk], SPB);
    cnt[tid] = 0;
    __syncthreads();
    for (int i = tid; i < n; i += 256) {
        int lr = ((unsigned)spack[bb + i].x) >> 17;
        atomicAdd(&cnt[lr], 1);
    }
    __syncthreads();
    int v = cnt[tid];
    sm[tid] = v;
    __syncthreads();
    for (int off = 1; off < 256; off <<= 1) {
        int t = (tid >= off) ? sm[tid - off] : 0;
        __syncthreads();
        sm[tid] += t;
        __syncthreads();
    }
    int ex = sm[tid] - v;
    cur[tid] = ex;
    int grow = buk * 256 + tid;
    if (grow < NN) {
        row_beg[grow] = (int)bb + ex;
        row_cnt[grow] = v;
    }
    __syncthreads();
    for (int i = tid; i < n; i += 256) {
        int2 p = spack[bb + i];
        int lr = ((unsigned)p.x) >> 17;
        int pos = atomicAdd(&cur[lr], 1);
        int2 q;
        q.x = p.x & COLMASK;
        q.y = p.y;
        cpack[bb + pos] = q;
    }
}

// ---------------- W1 -> bf16 transposed [HID][FIN] ----------------
__global__ __launch_bounds__(256) void k_w1t(const float* __restrict__ W1, unsigned short* __restrict__ W1T) {
    int b = blockIdx.x;     // 32 blocks, 16 k each
    int n = threadIdx.x;
    unsigned short tmp[16];
#pragma unroll
    for (int kk = 0; kk < 16; kk++)
        tmp[kk] = f2bfu(W1[(size_t)(b * 16 + kk) * HID + n]);
    unsigned short* dst = W1T + (size_t)n * FIN + b * 16;
    *(short8*)dst = *(short8*)tmp;
    *(short8*)(dst + 8) = *(short8*)(tmp + 8);
}

// ---------------- GEMM1: h1 = int8( bf16(x) @ W1T ), scale 16 ----------------
// block tile 64x256, 4 waves in 2x2, each wave 32x128 (acc[2][8] = 64 AGPRs)
__global__ __launch_bounds__(256, 3) void k_gemm1(const float* __restrict__ x, const unsigned short* __restrict__ W1T,
                                                  signed char* __restrict__ h1) {
    __shared__ unsigned short As[64][40];
    __shared__ unsigned short Bs[256][40];
    const int tid = threadIdx.x;
    const int row0 = blockIdx.x * 64;
    const int lane = tid & 63;
    const int w = tid >> 6;
    const int wr = (w >> 1) * 32;     // wave row offset
    const int wc = (w & 1) * 128;     // wave col offset
    const int m16 = lane & 15;
    const int quad = lane >> 4;

    f32x4 acc[2][8];
#pragma unroll
    for (int i = 0; i < 2; i++)
#pragma unroll
        for (int j = 0; j < 8; j++) acc[i][j] = (f32x4){0.f, 0.f, 0.f, 0.f};

    for (int k0 = 0; k0 < FIN; k0 += 32) {
        __syncthreads();
        // stage A: 64 rows x 32 k, fp32 -> bf16 (2 float4 per thread)
#pragma unroll
        for (int rep = 0; rep < 2; rep++) {
            int i = tid + rep * 256;
            int r = i >> 3;
            int ks = (i & 7) * 4;
            int gr = row0 + r;
            if (gr >= NN) gr = NN - 1;
            const float4 v = *(const float4*)(x + (size_t)gr * FIN + k0 + ks);
            ushort4 b;
            b.x = f2bfu(v.x); b.y = f2bfu(v.y); b.z = f2bfu(v.z); b.w = f2bfu(v.w);
            *(ushort4*)(&As[r][ks]) = b;
        }
        // stage B from pre-transposed bf16 W1T: thread n loads 32 contiguous k (64 B)
        {
            const unsigned short* wp = W1T + (size_t)tid * FIN + k0;
#pragma unroll
            for (int j = 0; j < 4; j++)
                *(short8*)(&Bs[tid][j * 8]) = *(const short8*)(wp + j * 8);
        }
        __syncthreads();
        short8 af[2], bfr[8];
#pragma unroll
        for (int i = 0; i < 2; i++) af[i] = *(const short8*)(&As[wr + i * 16 + m16][quad * 8]);
#pragma unroll
        for (int j = 0; j < 8; j++) bfr[j] = *(const short8*)(&Bs[wc + j * 16 + m16][quad * 8]);
#pragma unroll
        for (int i = 0; i < 2; i++)
#pragma unroll
            for (int j = 0; j < 8; j++)
                acc[i][j] = __builtin_amdgcn_mfma_f32_16x16x32_bf16(af[i], bfr[j], acc[i][j], 0, 0, 0);
    }
    // epilogue: C/D layout col=lane&15, row=quad*4+reg; quantize to int8 scale 16
#pragma unroll
    for (int i = 0; i < 2; i++) {
#pragma unroll
        for (int r = 0; r < 4; r++) {
            int gr = row0 + wr + i * 16 + quad * 4 + r;
            if (gr < NN) {
#pragma unroll
                for (int j = 0; j < 8; j++) {
                    int c = wc + j * 16 + m16;
                    h1[(size_t)gr * HID + c] = q8(acc[i][j][r], 16.f);
                }
            }
        }
    }
}

// ---------------- SpMM1: a1 = relu(A @ h1/16 + b1) ----------------
// quarter-wave rows: 4 rows per wave, 16 lanes per row, dwordx4 gathers (1 KB/instr)
__global__ __launch_bounds__(256) void k_spmm1(const signed char* __restrict__ h1,
                                               const int2* __restrict__ cpack,
                                               const int* __restrict__ row_beg, const int* __restrict__ row_cnt,
                                               const float* __restrict__ b1, unsigned short* __restrict__ a1) {
    const int lane = threadIdx.x & 63;
    const int q = lane >> 4;           // quarter 0..3 -> row within wave
    const int t = lane & 15;           // column group: cols t*16..t*16+15
    const int row = ((int)(blockIdx.x * 256 + threadIdx.x) >> 6) * 4 + q;
    if (row >= NN) return;
    const int beg = row_beg[row];
    const int end = beg + row_cnt[row];
    float s[16];
#pragma unroll
    for (int i = 0; i < 16; i++) s[i] = 0.f;
    const signed char* hp = h1 + t * 16;
    int e = beg;
    for (; e + 8 <= end; e += 8) {
        unsigned long long m[8];
#pragma unroll
        for (int j = 0; j < 8; j++)
            m[j] = __builtin_nontemporal_load((const unsigned long long*)(cpack + e + j));
        int4 g[8];
#pragma unroll
        for (int j = 0; j < 8; j++) {
            unsigned c = (unsigned)m[j];               // col < 2^17
            g[j] = *(const int4*)(hp + (size_t)(c << 8));
        }
#pragma unroll
        for (int j = 0; j < 8; j++) {
            const float v = __builtin_bit_cast(float, (unsigned)(m[j] >> 32)) * 0.0625f;
#pragma unroll
            for (int d = 0; d < 4; d++) {
                const int r = ((const int*)&g[j])[d];
                s[d * 4 + 0] = fmaf(v, (float)((r << 24) >> 24), s[d * 4 + 0]);
                s[d * 4 + 1] = fmaf(v, (float)((r << 16) >> 24), s[d * 4 + 1]);
                s[d * 4 + 2] = fmaf(v, (float)((r << 8) >> 24), s[d * 4 + 2]);
                s[d * 4 + 3] = fmaf(v, (float)(r >> 24), s[d * 4 + 3]);
            }
        }
    }
    for (; e < end; e++) {
        int2 mm = cpack[e];
        const float v = __builtin_bit_cast(float, mm.y) * 0.0625f;
        int4 gg = *(const int4*)(hp + ((size_t)(unsigned)mm.x << 8));
#pragma unroll
        for (int d = 0; d < 4; d++) {
            const int r = ((const int*)&gg)[d];
            s[d * 4 + 0] = fmaf(v, (float)((r << 24) >> 24), s[d * 4 + 0]);
            s[d * 4 + 1] = fmaf(v, (float)((r << 16) >> 24), s[d * 4 + 1]);
            s[d * 4 + 2] = fmaf(v, (float)((r << 8) >> 24), s[d * 4 + 2]);
            s[d * 4 + 3] = fmaf(v, (float)(r >> 24), s[d * 4 + 3]);
        }
    }
    const int col = t * 16;
    unsigned short o[16];
#pragma unroll
    for (int d = 0; d < 4; d++) {
        const float4 bb = *(const float4*)(b1 + col + d * 4);
        o[d * 4 + 0] = f2bfu(fmaxf(s[d * 4 + 0] + bb.x, 0.f));
        o[d * 4 + 1] = f2bfu(fmaxf(s[d * 4 + 1] + bb.y, 0.f));
        o[d * 4 + 2] = f2bfu(fmaxf(s[d * 4 + 2] + bb.z, 0.f));
        o[d * 4 + 3] = f2bfu(fmaxf(s[d * 4 + 3] + bb.w, 0.f));
    }
    unsigned short* op = a1 + (size_t)row * HID + col;
    *(short8*)op = *(short8*)o;
    *(short8*)(op + 8) = *(short8*)(o + 8);
}

// ---------------- GEMM2: h2 = int8( a1 @ W2 ), scale 4, 64 B padded rows ----------------
__global__ __launch_bounds__(256) void k_gemm2(const unsigned short* __restrict__ a1,
                                               const float* __restrict__ W2, signed char* __restrict__ h2) {
    __shared__ float ws[HID * NC];
    for (int i = threadIdx.x; i < HID * NC; i += 256) ws[i] = W2[i];
    __syncthreads();
    int r = blockIdx.x * 32 + (threadIdx.x >> 3);  // 3125*32 == 100000
    int c0 = (threadIdx.x & 7) * 5;
    float acc[5] = {0.f, 0.f, 0.f, 0.f, 0.f};
    const unsigned short* ap = a1 + (size_t)r * HID;
    for (int k4 = 0; k4 < HID / 4; k4++) {
        ushort4 av = *(const ushort4*)(ap + k4 * 4);
        float a0 = bf2f(av.x), a1f = bf2f(av.y), a2 = bf2f(av.z), a3 = bf2f(av.w);
        const float* wp = ws + (k4 * 4) * NC + c0;
#pragma unroll
        for (int j = 0; j < 5; j++)
            acc[j] = fmaf(a0, wp[j],
                     fmaf(a1f, wp[NC + j],
                     fmaf(a2, wp[2 * NC + j],
                     fmaf(a3, wp[3 * NC + j], acc[j]))));
    }
    signed char* op = h2 + (size_t)r * 64 + c0;
#pragma unroll
    for (int j = 0; j < 5; j++) op[j] = q8(acc[j], 4.f);
}

// ---------------- SpMM2 + bias + log_softmax ----------------
// quarter-wave rows: 4 rows per wave, 16 lanes per row, dword gathers (256 B/instr)
__global__ __launch_bounds__(256) void k_spmm2(const signed char* __restrict__ h2,
                                               const int2* __restrict__ cpack,
                                               const int* __restrict__ row_beg, const int* __restrict__ row_cnt,
                                               const float* __restrict__ b2, float* __restrict__ out) {
    const int lane = threadIdx.x & 63;
    const int q = lane >> 4;
    const int t = lane & 15;
    const int row = ((int)(blockIdx.x * 256 + threadIdx.x) >> 6) * 4 + q;
    if (row >= NN) return;
    const bool act = t < 10;           // 10 lanes x 4 cols = NC=40
    const int off = t * 4;             // byte/col offset within padded 64 B row
    const int boff = act ? off : 0;    // clamp for b2 reads
    const int beg = row_beg[row];
    const int end = beg + row_cnt[row];
    float a[4] = {0.f, 0.f, 0.f, 0.f};
    const signed char* hp = h2 + off;  // off <= 60, stays within 64 B padded row
    int e = beg;
    for (; e + 8 <= end; e += 8) {
        unsigned long long m[8];
#pragma unroll
        for (int j = 0; j < 8; j++)
            m[j] = __builtin_nontemporal_load((const unsigned long long*)(cpack + e + j));
        int g[8];
#pragma unroll
        for (int j = 0; j < 8; j++) {
            unsigned c = (unsigned)m[j];
            g[j] = *(const int*)(hp + (size_t)(c << 6));
        }
#pragma unroll
        for (int j = 0; j < 8; j++) {
            const float v = __builtin_bit_cast(float, (unsigned)(m[j] >> 32)) * 0.25f;
            const int r = g[j];
            a[0] = fmaf(v, (float)((r << 24) >> 24), a[0]);
            a[1] = fmaf(v, (float)((r << 16) >> 24), a[1]);
            a[2] = fmaf(v, (float)((r << 8) >> 24), a[2]);
            a[3] = fmaf(v, (float)(r >> 24), a[3]);
        }
    }
    for (; e < end; e++) {
        int2 mm = cpack[e];
        const float v = __builtin_bit_cast(float, mm.y) * 0.25f;
        const int r = *(const int*)(hp + ((size_t)(unsigned)mm.x << 6));
        a[0] = fmaf(v, (float)((r << 24) >> 24), a[0]);
        a[1] = fmaf(v, (float)((r << 16) >> 24), a[1]);
        a[2] = fmaf(v, (float)((r << 8) >> 24), a[2]);
        a[3] = fmaf(v, (float)(r >> 24), a[3]);
    }
    const float4 bb = *(const float4*)(b2 + boff);
    float acc[4];
    acc[0] = a[0] + bb.x; acc[1] = a[1] + bb.y; acc[2] = a[2] + bb.z; acc[3] = a[3] + bb.w;
    float mx = act ? fmaxf(fmaxf(acc[0], acc[1]), fmaxf(acc[2], acc[3])) : -INFINITY;
#pragma unroll
    for (int o = 1; o < 16; o <<= 1) mx = fmaxf(mx, __shfl_xor(mx, o, 16));
    float se = 0.f;
    if (act) {
#pragma unroll
        for (int i = 0; i < 4; i++) se += expf(acc[i] - mx);
    }
#pragma unroll
    for (int o = 1; o < 16; o <<= 1) se += __shfl_xor(se, o, 16);
    const float ls = logf(se);
    if (act) {
        float4 r;
        r.x = acc[0] - mx - ls;
        r.y = acc[1] - mx - ls;
        r.z = acc[2] - mx - ls;
        r.w = acc[3] - mx - ls;
        *(float4*)(out + (size_t)row * NC + off) = r;
    }
}

extern "C" void kernel_launch(void* const* d_in, const int* in_sizes, int n_in, void* d_out, int out_size,
                              void* d_ws, size_t ws_size, hipStream_t stream) {
    const float* x  = (const float*)d_in[0];
    const int*   er = (const int*)d_in[1];
    const int*   ec = (const int*)d_in[2];
    const float* ev = (const float*)d_in[3];
    const float* W1 = (const float*)d_in[4];
    const float* b1 = (const float*)d_in[5];
    const float* W2 = (const float*)d_in[6];
    const float* b2 = (const float*)d_in[7];
    float* out = (float*)d_out;
    char* ws = (char*)d_ws;

    // spack (29.6 MB) aliases h1 (25.6 MB): finecsr finishes reading spack
    // before gemm1 writes h1 (stream-ordered).
    int2*  spack       = (int2*)(ws + 0);                     // 29,628,416 B
    signed char* h1    = (signed char*)(ws + 0);              // 25,600,000 B (aliased)
    unsigned short* a1 = (unsigned short*)(ws + 29628416);    // 51,200,000 B
    signed char* h2    = (signed char*)(ws + 80828416);       //  6,400,000 B (64 B rows)
    int2*  cpack       = (int2*)(ws + 87228416);              // 29,628,416 B
    int*   row_beg     = (int*)(ws + 116856832);              // 400,000 B
    int*   row_cnt     = (int*)(ws + 117256832);              // 400,000 B
    int*   bcnt        = (int*)(ws + 117656832);              // 2,048 B
    unsigned short* W1T = (unsigned short*)(ws + 117658880);  // 262,144 B

    hipMemsetAsync(bcnt, 0, NBUK * sizeof(int), stream);
    k_w1t<<<32, 256, 0, stream>>>(W1, W1T);
    k_bin<<<BIN_BLOCKS, 256, 0, stream>>>(er, ec, ev, bcnt, spack);
    k_finecsr<<<NBUK, 256, 0, stream>>>(spack, bcnt, cpack, row_beg, row_cnt);
    k_gemm1<<<(NN + 63) / 64, 256, 0, stream>>>(x, W1T, h1);
    k_spmm1<<<(NN + 15) / 16, 256, 0, stream>>>(h1, cpack, row_beg, row_cnt, b1, a1);
    k_gemm2<<<NN / 32, 256, 0, stream>>>(a1, W2, h2);
    k_spmm2<<<(NN + 15) / 16, 256, 0, stream>>>(h2, cpack, row_beg, row_cnt, b2, out);
}

// Round 2
// 654.850 us; speedup vs baseline: 1.2148x; 1.1168x over previous
//
#include <hip/hip_runtime.h>
#include <math.h>

#define NN  100000
#define NE  3200000
#define FIN 512
#define HID 256
#define NC  40

#define NBUK 391                      // ceil(NN/256), bucket = row>>8
#define SPB  9472                     // fixed slots per bucket (mean 8184 + 14 sigma)
#define BIN_BLOCKS 512
#define CHUNK ((NE + BIN_BLOCKS - 1) / BIN_BLOCKS)   // 6250
#define COLMASK 0x1FFFF

typedef __attribute__((ext_vector_type(8))) short short8;
typedef __attribute__((ext_vector_type(4))) float f32x4;

__device__ inline float bf2f(unsigned short u) {
    unsigned int x = ((unsigned int)u) << 16;
    return __builtin_bit_cast(float, x);
}
__device__ inline unsigned short f2bfu(float f) {
    unsigned int x = __builtin_bit_cast(unsigned int, f);
    unsigned int r = (x + 0x7fffu + ((x >> 16) & 1u)) >> 16;
    return (unsigned short)r;
}
__device__ inline signed char q8(float v, float s) {
    int q = (int)rintf(v * s);
    q = max(-127, min(127, q));
    return (signed char)q;
}
__device__ inline unsigned cvtpk_bf16(float lo, float hi) {
    unsigned r;
    asm("v_cvt_pk_bf16_f32 %0, %1, %2" : "=v"(r) : "v"(lo), "v"(hi));
    return r;
}

// ---------------- bin edges into fixed-stride bucket staging (no pre-scan) ----------------
__global__ __launch_bounds__(256) void k_bin(const int* __restrict__ er, const int* __restrict__ ec,
                                             const float* __restrict__ ev, int* __restrict__ bcnt,
                                             int2* __restrict__ spack) {
    __shared__ int hist[NBUK];
    __shared__ int base[NBUK];
    __shared__ int lcur[NBUK];
    for (int i = threadIdx.x; i < NBUK; i += 256) { hist[i] = 0; lcur[i] = 0; }
    __syncthreads();
    int start = blockIdx.x * CHUNK;
    int end = min(start + CHUNK, NE);
    for (int e = start + threadIdx.x; e < end; e += 256)
        atomicAdd(&hist[er[e] >> 8], 1);
    __syncthreads();
    for (int i = threadIdx.x; i < NBUK; i += 256) {
        int h = hist[i];
        base[i] = h ? atomicAdd(&bcnt[i], h) : 0;
    }
    __syncthreads();
    for (int e = start + threadIdx.x; e < end; e += 256) {
        int r = er[e];
        int b = r >> 8;
        int ofs = atomicAdd(&lcur[b], 1);
        int2 p;
        p.x = ((r & 255) << 17) | ec[e];
        p.y = __builtin_bit_cast(int, ev[e]);
        spack[(size_t)b * SPB + base[b] + ofs] = p;
    }
}

// ---------------- fine CSR within each bucket ----------------
__global__ __launch_bounds__(256) void k_finecsr(const int2* __restrict__ spack, const int* __restrict__ bcnt,
                                                 int2* __restrict__ cpack,
                                                 int* __restrict__ row_beg, int* __restrict__ row_cnt) {
    __shared__ int cnt[256];
    __shared__ int sm[256];
    __shared__ int cur[256];
    int tid = threadIdx.x;
    int buk = blockIdx.x;
    size_t bb = (size_t)buk * SPB;
    int n = min(bcnt[buk], SPB);
    cnt[tid] = 0;
    __syncthreads();
    for (int i = tid; i < n; i += 256) {
        int lr = ((unsigned)spack[bb + i].x) >> 17;
        atomicAdd(&cnt[lr], 1);
    }
    __syncthreads();
    int v = cnt[tid];
    sm[tid] = v;
    __syncthreads();
    for (int off = 1; off < 256; off <<= 1) {
        int t = (tid >= off) ? sm[tid - off] : 0;
        __syncthreads();
        sm[tid] += t;
        __syncthreads();
    }
    int ex = sm[tid] - v;
    cur[tid] = ex;
    int grow = buk * 256 + tid;
    if (grow < NN) {
        row_beg[grow] = (int)bb + ex;
        row_cnt[grow] = v;
    }
    __syncthreads();
    for (int i = tid; i < n; i += 256) {
        int2 p = spack[bb + i];
        int lr = ((unsigned)p.x) >> 17;
        int pos = atomicAdd(&cur[lr], 1);
        int2 q;
        q.x = p.x & COLMASK;
        q.y = p.y;
        cpack[bb + pos] = q;
    }
}

// ---------------- W1 -> bf16 transposed [HID][FIN] ----------------
__global__ __launch_bounds__(256) void k_w1t(const float* __restrict__ W1, unsigned short* __restrict__ W1T) {
    int b = blockIdx.x;     // 32 blocks, 16 k each
    int n = threadIdx.x;
    unsigned short tmp[16];
#pragma unroll
    for (int kk = 0; kk < 16; kk++)
        tmp[kk] = f2bfu(W1[(size_t)(b * 16 + kk) * HID + n]);
    unsigned short* dst = W1T + (size_t)n * FIN + b * 16;
    *(short8*)dst = *(short8*)tmp;
    *(short8*)(dst + 8) = *(short8*)(tmp + 8);
}

// ---------------- W2 -> bf16 transposed [48][HID] (cols >= NC zero) ----------------
__global__ __launch_bounds__(256) void k_w2t(const float* __restrict__ W2, unsigned short* __restrict__ W2T) {
    int n = blockIdx.x;      // 0..47
    int k = threadIdx.x;     // 0..255
    float v = (n < NC) ? W2[(size_t)k * NC + n] : 0.f;
    W2T[(size_t)n * HID + k] = f2bfu(v);
}

// ---------------- GEMM1: h1 = int8( bf16(x) @ W1T ), scale 16 ----------------
// 128x128 tile (grid 782 x 2 over N=256), 4 waves 2x2, wave 64x64 acc[4][4].
// Double-buffered LDS (80 B row stride -> 2-way bank alias = free), one barrier
// per K-step; global loads for tile t+2 issued while tile t computes.
__global__ __launch_bounds__(256) void k_gemm1(const float* __restrict__ x, const unsigned short* __restrict__ W1T,
                                               signed char* __restrict__ h1) {
    __shared__ unsigned short As[2][128][40];
    __shared__ unsigned short Bs[2][128][40];
    const int tid = threadIdx.x;
    const int row0 = (blockIdx.x >> 1) * 128;
    const int col0 = (blockIdx.x & 1) * 128;
    const int lane = tid & 63;
    const int w = tid >> 6;
    const int wr = (w >> 1) * 64;
    const int wc = (w & 1) * 64;
    const int m16 = lane & 15;
    const int quad = lane >> 4;

    // staging: thread t covers row tid>>1, k-halves (tid&1)*16 .. +16
    const int srow = tid >> 1;
    const int skoff = (tid & 1) * 16;
    int gar = row0 + srow;
    if (gar >= NN) gar = NN - 1;
    const float* ax = x + (size_t)gar * FIN + skoff;
    const unsigned short* bw = W1T + (size_t)(col0 + srow) * FIN + skoff;

    f32x4 acc[4][4];
#pragma unroll
    for (int i = 0; i < 4; i++)
#pragma unroll
        for (int j = 0; j < 4; j++) acc[i][j] = (f32x4){0.f, 0.f, 0.f, 0.f};

    float4 va[4];
    uint4 vb0, vb1;

#define G1_LOAD(tt)                                                        \
    {                                                                      \
        const float* ap = ax + (tt) * 32;                                  \
        va[0] = *(const float4*)(ap);                                      \
        va[1] = *(const float4*)(ap + 4);                                  \
        va[2] = *(const float4*)(ap + 8);                                  \
        va[3] = *(const float4*)(ap + 12);                                 \
        const unsigned short* bp = bw + (tt) * 32;                         \
        vb0 = *(const uint4*)(bp);                                         \
        vb1 = *(const uint4*)(bp + 8);                                     \
    }

#define G1_STORE(bf)                                                       \
    {                                                                      \
        uint4 pa0, pa1;                                                    \
        pa0.x = cvtpk_bf16(va[0].x, va[0].y);                              \
        pa0.y = cvtpk_bf16(va[0].z, va[0].w);                              \
        pa0.z = cvtpk_bf16(va[1].x, va[1].y);                              \
        pa0.w = cvtpk_bf16(va[1].z, va[1].w);                              \
        pa1.x = cvtpk_bf16(va[2].x, va[2].y);                              \
        pa1.y = cvtpk_bf16(va[2].z, va[2].w);                              \
        pa1.z = cvtpk_bf16(va[3].x, va[3].y);                              \
        pa1.w = cvtpk_bf16(va[3].z, va[3].w);                              \
        *(uint4*)(&As[bf][srow][skoff]) = pa0;                             \
        *(uint4*)(&As[bf][srow][skoff + 8]) = pa1;                         \
        *(uint4*)(&Bs[bf][srow][skoff]) = vb0;                             \
        *(uint4*)(&Bs[bf][srow][skoff + 8]) = vb1;                         \
    }

    // prologue: tile 0 staged, tile 1 in regs
    G1_LOAD(0)
    G1_STORE(0)
    G1_LOAD(1)
    __syncthreads();

    for (int t = 0; t < 16; ++t) {
        const int buf = t & 1;
        short8 af[4], bfr[4];
#pragma unroll
        for (int i = 0; i < 4; i++) af[i] = *(const short8*)(&As[buf][wr + i * 16 + m16][quad * 8]);
#pragma unroll
        for (int j = 0; j < 4; j++) bfr[j] = *(const short8*)(&Bs[buf][wc + j * 16 + m16][quad * 8]);
        if (t < 15) {
            G1_STORE(buf ^ 1)          // consumes regs of tile t+1 (vmcnt wait inserted)
            if (t < 14) G1_LOAD(t + 2) // issue tile t+2, hides under MFMA + next iter
        }
#pragma unroll
        for (int i = 0; i < 4; i++)
#pragma unroll
            for (int j = 0; j < 4; j++)
                acc[i][j] = __builtin_amdgcn_mfma_f32_16x16x32_bf16(af[i], bfr[j], acc[i][j], 0, 0, 0);
        __syncthreads();
    }
#undef G1_LOAD
#undef G1_STORE

    // epilogue: C/D layout col=lane&15, row=quad*4+reg; quantize to int8 scale 16
#pragma unroll
    for (int i = 0; i < 4; i++) {
#pragma unroll
        for (int r = 0; r < 4; r++) {
            int gr = row0 + wr + i * 16 + quad * 4 + r;
            if (gr < NN) {
#pragma unroll
                for (int j = 0; j < 4; j++) {
                    int c = col0 + wc + j * 16 + m16;
                    h1[(size_t)gr * HID + c] = q8(acc[i][j][r], 16.f);
                }
            }
        }
    }
}

// ---------------- SpMM1: a1 = relu(A @ h1/16 + b1) ----------------
// quarter-wave rows: 4 rows per wave, 16 lanes per row, dwordx4 gathers (1 KB/instr)
__global__ __launch_bounds__(256) void k_spmm1(const signed char* __restrict__ h1,
                                               const int2* __restrict__ cpack,
                                               const int* __restrict__ row_beg, const int* __restrict__ row_cnt,
                                               const float* __restrict__ b1, unsigned short* __restrict__ a1) {
    const int lane = threadIdx.x & 63;
    const int q = lane >> 4;           // quarter 0..3 -> row within wave
    const int t = lane & 15;           // column group: cols t*16..t*16+15
    const int row = ((int)(blockIdx.x * 256 + threadIdx.x) >> 6) * 4 + q;
    if (row >= NN) return;
    const int beg = row_beg[row];
    const int end = beg + row_cnt[row];
    float s[16];
#pragma unroll
    for (int i = 0; i < 16; i++) s[i] = 0.f;
    const signed char* hp = h1 + t * 16;
    int e = beg;
    for (; e + 8 <= end; e += 8) {
        unsigned long long m[8];
#pragma unroll
        for (int j = 0; j < 8; j++)
            m[j] = __builtin_nontemporal_load((const unsigned long long*)(cpack + e + j));
        int4 g[8];
#pragma unroll
        for (int j = 0; j < 8; j++) {
            unsigned c = (unsigned)m[j];               // col < 2^17
            g[j] = *(const int4*)(hp + (size_t)(c << 8));
        }
#pragma unroll
        for (int j = 0; j < 8; j++) {
            const float v = __builtin_bit_cast(float, (unsigned)(m[j] >> 32)) * 0.0625f;
#pragma unroll
            for (int d = 0; d < 4; d++) {
                const int r = ((const int*)&g[j])[d];
                s[d * 4 + 0] = fmaf(v, (float)((r << 24) >> 24), s[d * 4 + 0]);
                s[d * 4 + 1] = fmaf(v, (float)((r << 16) >> 24), s[d * 4 + 1]);
                s[d * 4 + 2] = fmaf(v, (float)((r << 8) >> 24), s[d * 4 + 2]);
                s[d * 4 + 3] = fmaf(v, (float)(r >> 24), s[d * 4 + 3]);
            }
        }
    }
    for (; e < end; e++) {
        int2 mm = cpack[e];
        const float v = __builtin_bit_cast(float, mm.y) * 0.0625f;
        int4 gg = *(const int4*)(hp + ((size_t)(unsigned)mm.x << 8));
#pragma unroll
        for (int d = 0; d < 4; d++) {
            const int r = ((const int*)&gg)[d];
            s[d * 4 + 0] = fmaf(v, (float)((r << 24) >> 24), s[d * 4 + 0]);
            s[d * 4 + 1] = fmaf(v, (float)((r << 16) >> 24), s[d * 4 + 1]);
            s[d * 4 + 2] = fmaf(v, (float)((r << 8) >> 24), s[d * 4 + 2]);
            s[d * 4 + 3] = fmaf(v, (float)(r >> 24), s[d * 4 + 3]);
        }
    }
    const int col = t * 16;
    unsigned short o[16];
#pragma unroll
    for (int d = 0; d < 4; d++) {
        const float4 bb = *(const float4*)(b1 + col + d * 4);
        o[d * 4 + 0] = f2bfu(fmaxf(s[d * 4 + 0] + bb.x, 0.f));
        o[d * 4 + 1] = f2bfu(fmaxf(s[d * 4 + 1] + bb.y, 0.f));
        o[d * 4 + 2] = f2bfu(fmaxf(s[d * 4 + 2] + bb.z, 0.f));
        o[d * 4 + 3] = f2bfu(fmaxf(s[d * 4 + 3] + bb.w, 0.f));
    }
    unsigned short* op = a1 + (size_t)row * HID + col;
    *(short8*)op = *(short8*)o;
    *(short8*)(op + 8) = *(short8*)(o + 8);
}

// ---------------- GEMM2: h2 = int8( a1 @ W2T^T ), scale 4, MFMA, frags from global ----------------
// block = 4 waves x 64 rows = 256 rows; N=40 padded to 48 (3 n-tiles)
__global__ __launch_bounds__(256) void k_gemm2(const unsigned short* __restrict__ a1,
                                               const unsigned short* __restrict__ W2T, signed char* __restrict__ h2) {
    const int tid = threadIdx.x;
    const int lane = tid & 63;
    const int w = tid >> 6;
    const int m16 = lane & 15;
    const int quad = lane >> 4;
    const int r0 = blockIdx.x * 256 + w * 64;

    f32x4 acc[4][3];
#pragma unroll
    for (int i = 0; i < 4; i++)
#pragma unroll
        for (int j = 0; j < 3; j++) acc[i][j] = (f32x4){0.f, 0.f, 0.f, 0.f};

    for (int k0 = 0; k0 < HID; k0 += 32) {
        short8 af[4], bfr[3];
#pragma unroll
        for (int i = 0; i < 4; i++) {
            int gr = r0 + i * 16 + m16;
            if (gr >= NN) gr = NN - 1;
            af[i] = *(const short8*)(a1 + (size_t)gr * HID + k0 + quad * 8);
        }
#pragma unroll
        for (int j = 0; j < 3; j++)
            bfr[j] = *(const short8*)(W2T + (size_t)(j * 16 + m16) * HID + k0 + quad * 8);
#pragma unroll
        for (int i = 0; i < 4; i++)
#pragma unroll
            for (int j = 0; j < 3; j++)
                acc[i][j] = __builtin_amdgcn_mfma_f32_16x16x32_bf16(af[i], bfr[j], acc[i][j], 0, 0, 0);
    }
#pragma unroll
    for (int i = 0; i < 4; i++) {
#pragma unroll
        for (int r = 0; r < 4; r++) {
            int gr = r0 + i * 16 + quad * 4 + r;
            if (gr < NN) {
#pragma unroll
                for (int j = 0; j < 3; j++) {
                    int c = j * 16 + m16;
                    if (c < NC) h2[(size_t)gr * 64 + c] = q8(acc[i][j][r], 4.f);
                }
            }
        }
    }
}

// ---------------- SpMM2 + bias + log_softmax ----------------
// quarter-wave rows: 4 rows per wave, 16 lanes per row, dword gathers (256 B/instr)
__global__ __launch_bounds__(256) void k_spmm2(const signed char* __restrict__ h2,
                                               const int2* __restrict__ cpack,
                                               const int* __restrict__ row_beg, const int* __restrict__ row_cnt,
                                               const float* __restrict__ b2, float* __restrict__ out) {
    const int lane = threadIdx.x & 63;
    const int q = lane >> 4;
    const int t = lane & 15;
    const int row = ((int)(blockIdx.x * 256 + threadIdx.x) >> 6) * 4 + q;
    if (row >= NN) return;
    const bool act = t < 10;           // 10 lanes x 4 cols = NC=40
    const int off = t * 4;             // byte/col offset within padded 64 B row
    const int boff = act ? off : 0;    // clamp for b2 reads
    const int beg = row_beg[row];
    const int end = beg + row_cnt[row];
    float a[4] = {0.f, 0.f, 0.f, 0.f};
    const signed char* hp = h2 + off;  // off <= 60, stays within 64 B padded row
    int e = beg;
    for (; e + 8 <= end; e += 8) {
        unsigned long long m[8];
#pragma unroll
        for (int j = 0; j < 8; j++)
            m[j] = __builtin_nontemporal_load((const unsigned long long*)(cpack + e + j));
        int g[8];
#pragma unroll
        for (int j = 0; j < 8; j++) {
            unsigned c = (unsigned)m[j];
            g[j] = *(const int*)(hp + (size_t)(c << 6));
        }
#pragma unroll
        for (int j = 0; j < 8; j++) {
            const float v = __builtin_bit_cast(float, (unsigned)(m[j] >> 32)) * 0.25f;
            const int r = g[j];
            a[0] = fmaf(v, (float)((r << 24) >> 24), a[0]);
            a[1] = fmaf(v, (float)((r << 16) >> 24), a[1]);
            a[2] = fmaf(v, (float)((r << 8) >> 24), a[2]);
            a[3] = fmaf(v, (float)(r >> 24), a[3]);
        }
    }
    for (; e < end; e++) {
        int2 mm = cpack[e];
        const float v = __builtin_bit_cast(float, mm.y) * 0.25f;
        const int r = *(const int*)(hp + ((size_t)(unsigned)mm.x << 6));
        a[0] = fmaf(v, (float)((r << 24) >> 24), a[0]);
        a[1] = fmaf(v, (float)((r << 16) >> 24), a[1]);
        a[2] = fmaf(v, (float)((r << 8) >> 24), a[2]);
        a[3] = fmaf(v, (float)(r >> 24), a[3]);
    }
    const float4 bb = *(const float4*)(b2 + boff);
    float acc[4];
    acc[0] = a[0] + bb.x; acc[1] = a[1] + bb.y; acc[2] = a[2] + bb.z; acc[3] = a[3] + bb.w;
    float mx = act ? fmaxf(fmaxf(acc[0], acc[1]), fmaxf(acc[2], acc[3])) : -INFINITY;
#pragma unroll
    for (int o = 1; o < 16; o <<= 1) mx = fmaxf(mx, __shfl_xor(mx, o, 16));
    float se = 0.f;
    if (act) {
#pragma unroll
        for (int i = 0; i < 4; i++) se += expf(acc[i] - mx);
    }
#pragma unroll
    for (int o = 1; o < 16; o <<= 1) se += __shfl_xor(se, o, 16);
    const float ls = logf(se);
    if (act) {
        float4 r;
        r.x = acc[0] - mx - ls;
        r.y = acc[1] - mx - ls;
        r.z = acc[2] - mx - ls;
        r.w = acc[3] - mx - ls;
        *(float4*)(out + (size_t)row * NC + off) = r;
    }
}

extern "C" void kernel_launch(void* const* d_in, const int* in_sizes, int n_in, void* d_out, int out_size,
                              void* d_ws, size_t ws_size, hipStream_t stream) {
    const float* x  = (const float*)d_in[0];
    const int*   er = (const int*)d_in[1];
    const int*   ec = (const int*)d_in[2];
    const float* ev = (const float*)d_in[3];
    const float* W1 = (const float*)d_in[4];
    const float* b1 = (const float*)d_in[5];
    const float* W2 = (const float*)d_in[6];
    const float* b2 = (const float*)d_in[7];
    float* out = (float*)d_out;
    char* ws = (char*)d_ws;

    // spack (29.6 MB) aliases h1 (25.6 MB): finecsr finishes reading spack
    // before gemm1 writes h1 (stream-ordered).
    int2*  spack       = (int2*)(ws + 0);                     // 29,628,416 B
    signed char* h1    = (signed char*)(ws + 0);              // 25,600,000 B (aliased)
    unsigned short* a1 = (unsigned short*)(ws + 29628416);    // 51,200,000 B
    signed char* h2    = (signed char*)(ws + 80828416);       //  6,400,000 B (64 B rows)
    int2*  cpack       = (int2*)(ws + 87228416);              // 29,628,416 B
    int*   row_beg     = (int*)(ws + 116856832);              // 400,000 B
    int*   row_cnt     = (int*)(ws + 117256832);              // 400,000 B
    int*   bcnt        = (int*)(ws + 117656832);              // 2,048 B
    unsigned short* W1T = (unsigned short*)(ws + 117658880);  // 262,144 B
    unsigned short* W2T = (unsigned short*)(ws + 117921024);  //  24,576 B

    hipMemsetAsync(bcnt, 0, NBUK * sizeof(int), stream);
    k_w1t<<<32, 256, 0, stream>>>(W1, W1T);
    k_w2t<<<48, 256, 0, stream>>>(W2, W2T);
    k_bin<<<BIN_BLOCKS, 256, 0, stream>>>(er, ec, ev, bcnt, spack);
    k_finecsr<<<NBUK, 256, 0, stream>>>(spack, bcnt, cpack, row_beg, row_cnt);
    k_gemm1<<<1564, 256, 0, stream>>>(x, W1T, h1);
    k_spmm1<<<(NN + 15) / 16, 256, 0, stream>>>(h1, cpack, row_beg, row_cnt, b1, a1);
    k_gemm2<<<(NN + 255) / 256, 256, 0, stream>>>(a1, W2T, h2);
    k_spmm2<<<(NN + 15) / 16, 256, 0, stream>>>(h2, cpack, row_beg, row_cnt, b2, out);
}